// Round 10
// baseline (345.861 us; speedup 1.0000x reference)
//
#include <hip/hip_runtime.h>
#include <stdint.h>

// Problem constants (B=4, T=2048, C=1024, H=16, D=64)
#define T_SEQ 2048
#define CDIM  1024
#define NH    16
#define DH    64
#define BATCH 4
#define MROWS (BATCH * T_SEQ)   // 8192
#define N3    (3 * CDIM)        // 3072
#define NEGBIG -1e30f

typedef unsigned short u16;
typedef __attribute__((ext_vector_type(8))) __bf16 bf16x8;
typedef __attribute__((ext_vector_type(8))) unsigned short u16x8;
typedef __attribute__((ext_vector_type(4))) float f32x4;
typedef __attribute__((ext_vector_type(16))) float f32x16;
typedef __attribute__((ext_vector_type(4))) unsigned int u32x4;

__device__ inline u16 f2bf(float f) {
  uint32_t u = __builtin_bit_cast(uint32_t, f);
  u += 0x7FFFu + ((u >> 16) & 1u);   // RNE; inputs finite
  return (u16)(u >> 16);
}

// async global->LDS, 16B per lane; LDS dest = wave-uniform base + lane*16
__device__ inline void gld_lds16(const void* g, void* l) {
  __builtin_amdgcn_global_load_lds(
      (const __attribute__((address_space(1))) void*)g,
      (__attribute__((address_space(3))) void*)l, 16, 0, 0);
}

// ---------------- aux kernels ----------------

__global__ __launch_bounds__(256) void cvt_f32_bf16(
    const float* __restrict__ in, u16* __restrict__ out, int n) {
  int i = (blockIdx.x * 256 + threadIdx.x) * 4;
  if (i >= n) return;
  float4 v = *(const float4*)&in[i];
  ushort4 o; o.x = f2bf(v.x); o.y = f2bf(v.y); o.z = f2bf(v.z); o.w = f2bf(v.w);
  *(ushort4*)&out[i] = o;
}

// W [K][N] fp32 -> WT [N][K] bf16, LDS-tiled (coalesced both sides)
__global__ __launch_bounds__(256) void wt_tiled(
    const float* __restrict__ W, u16* __restrict__ WT, int K, int N) {
  __shared__ float tile[64][65];
  const int k0 = blockIdx.y * 64, n0 = blockIdx.x * 64;
  const int t = threadIdx.x, cr = t >> 6, cc = t & 63;
#pragma unroll
  for (int i = 0; i < 16; i++) {
    int r = i * 4 + cr;
    tile[r][cc] = W[(size_t)(k0 + r) * N + n0 + cc];
  }
  __syncthreads();
#pragma unroll
  for (int i = 0; i < 16; i++) {
    int r = i * 4 + cr;  // output row (n)
    WT[(size_t)(n0 + r) * K + k0 + cc] = f2bf(tile[cc][r]);
  }
}

// lengths[b] = count of non-padded rows; auto-detect int32 vs byte mask.
__global__ __launch_bounds__(256) void len_kernel(
    const void* __restrict__ maskp, int* __restrict__ lengths) {
  __shared__ int flag;
  __shared__ int red[256];
  const int t = threadIdx.x, b = blockIdx.x;
  if (t == 0) flag = 0;
  __syncthreads();
  const uint32_t* mw = (const uint32_t*)maskp;
  int f = 0;
  for (int i = t; i < 2048; i += 256) f |= (mw[i] > 1u) ? 1 : 0;
  if (f) atomicOr(&flag, 1);
  __syncthreads();
  int cnt = 0;
  if (flag) {
    const uint8_t* mb = (const uint8_t*)maskp;
    for (int i = t; i < T_SEQ; i += 256) cnt += (mb[(size_t)b * T_SEQ + i] == 0);
  } else {
    const int* mi = (const int*)maskp;
    for (int i = t; i < T_SEQ; i += 256) cnt += (mi[(size_t)b * T_SEQ + i] == 0);
  }
  red[t] = cnt;
  __syncthreads();
  for (int s = 128; s > 0; s >>= 1) {
    if (t < s) red[t] += red[t + s];
    __syncthreads();
  }
  if (t == 0) lengths[b] = red[0];
}

// ---------------- GEMM: C[M,N] = A[M,K] * Bt[N,K]^T + bias ----------------
// 128x128 tile, BK=64, 4 waves, mfma_f32_16x16x32_bf16, XOR-swizzled LDS.
// MODE 0: n<2048 -> scatter Q/K [b,h,t,d]; n>=2048 -> V transposed to
//         Vt [b,h,d,t] (t sigma-permuted: swap bits 2,3 of t&15, so attn's
//         PV reads one contiguous b128 per fragment). MODE 1: fp32 out.
template <int MODE>
__global__ __launch_bounds__(256, 2) void gemm_bf16(
    const u16* __restrict__ A, const u16* __restrict__ Bt,
    const float* __restrict__ bias,
    u16* __restrict__ Qb, u16* __restrict__ Kb, u16* __restrict__ Vt,
    float* __restrict__ Out, const int* __restrict__ lengths,
    int Mdim, int Ndim, int Kdim) {
  __shared__ u16 SM[16384];           // As = SM[0:8192], Bs = SM[8192:16384]
  u16* As = SM;
  u16* Bs = SM + 8192;
  const int t = threadIdx.x;
  const int lane = t & 63, wid = t >> 6;
  const int wr = wid >> 1, wc = wid & 1;
  const int r16 = lane & 15, kg = lane >> 4;
  const int m0 = blockIdx.y * 128, n0 = blockIdx.x * 128;

  f32x4 acc[4][4];
#pragma unroll
  for (int i = 0; i < 4; i++)
#pragma unroll
    for (int j = 0; j < 4; j++) acc[i][j] = (f32x4){0.f, 0.f, 0.f, 0.f};

  for (int k0 = 0; k0 < Kdim; k0 += 64) {
#pragma unroll
    for (int i = 0; i < 4; i++) {
      int idx = i * 256 + t;           // 0..1023
      int row = idx >> 3;              // 0..127
      int chunk = idx & 7;
      int colel = (chunk * 8) ^ ((row & 7) << 3);
      gld_lds16(&A[(size_t)(m0 + row) * Kdim + k0 + colel], &As[idx * 8]);
      gld_lds16(&Bt[(size_t)(n0 + row) * Kdim + k0 + colel], &Bs[idx * 8]);
    }
    __syncthreads();

#pragma unroll
    for (int s = 0; s < 2; s++) {
      bf16x8 af[4], bfr[4];
#pragma unroll
      for (int m = 0; m < 4; m++) {
        int row = wr * 64 + m * 16 + r16;
        int colel = (s * 32 + kg * 8) ^ ((row & 7) << 3);
        af[m] = *(const bf16x8*)&As[row * 64 + colel];
      }
#pragma unroll
      for (int n = 0; n < 4; n++) {
        int row = wc * 64 + n * 16 + r16;
        int colel = (s * 32 + kg * 8) ^ ((row & 7) << 3);
        bfr[n] = *(const bf16x8*)&Bs[row * 64 + colel];
      }
#pragma unroll
      for (int m = 0; m < 4; m++)
#pragma unroll
        for (int n = 0; n < 4; n++)
          acc[m][n] = __builtin_amdgcn_mfma_f32_16x16x32_bf16(
              af[m], bfr[n], acc[m][n], 0, 0, 0);
    }
    __syncthreads();
  }

  // epilogue: C/D layout col=lane&15, row=(lane>>4)*4+reg
  if (MODE == 0 && n0 >= 2048) {
    // V block -> transpose via LDS, write Vt[b,h,d,t'] (t' sigma-permuted)
    u16* Tt = SM;  // [128][128], chunk-swizzled
#pragma unroll
    for (int m = 0; m < 4; m++)
#pragma unroll
      for (int n = 0; n < 4; n++) {
        int ln = wc * 64 + n * 16 + r16;     // local n (d-ish)
        float bv = bias[n0 + ln];
#pragma unroll
        for (int reg = 0; reg < 4; reg++) {
          int lm = wr * 64 + m * 16 + kg * 4 + reg;  // local m (t)
          Tt[ln * 128 + (lm ^ ((ln & 7) << 3))] = f2bf(acc[m][n][reg] + bv);
        }
      }
    __syncthreads();
    const int b = m0 >> 11;
    const int tt0 = m0 & 2047;            // within-batch t offset
    const int cbase = n0 - 2048;
#pragma unroll
    for (int i = 0; i < 8; i++) {
      int u = i * 256 + t;
      int ln = u >> 4, ch = u & 15;
      u16x8 v = *(const u16x8*)&Tt[ln * 128 + ((ch * 8) ^ ((ln & 7) << 3))];
      int c = cbase + ln, hh = c >> 6, d = c & 63;
      size_t base = (((size_t)b * NH + hh) * DH + d) * T_SEQ;
      // sigma store: keys k0q..k0q+7 -> slots (swap bits 2,3 within t&15)
      int k0q = tt0 + ch * 8;
      int shift = (ch & 1) << 2;          // 0 (ch even) or 4 (ch odd)
      ushort4 qa; qa.x = (u16)v[0]; qa.y = (u16)v[1]; qa.z = (u16)v[2]; qa.w = (u16)v[3];
      ushort4 qb; qb.x = (u16)v[4]; qb.y = (u16)v[5]; qb.z = (u16)v[6]; qb.w = (u16)v[7];
      *(ushort4*)&Vt[base + k0q - shift] = qa;
      *(ushort4*)&Vt[base + k0q + 8 - shift] = qb;
    }
    return;
  }

#pragma unroll
  for (int m = 0; m < 4; m++) {
    int gmb = m0 + wr * 64 + m * 16 + kg * 4;
#pragma unroll
    for (int n = 0; n < 4; n++) {
      int gn = n0 + wc * 64 + n * 16 + r16;
      float bv = bias[gn];
#pragma unroll
      for (int reg = 0; reg < 4; reg++) {
        float v = acc[m][n][reg] + bv;
        int row = gmb + reg;           // = b*T + t
        int b = row >> 11, tt = row & 2047;
        if (MODE == 0) {
          int c = gn & 1023, h = c >> 6, d = c & 63;
          u16* dst = (gn < 1024) ? Qb : Kb;
          dst[((size_t)(b * NH + h) * T_SEQ + tt) * DH + d] = f2bf(v);
        } else {
          if (tt >= lengths[b]) v = 0.f;
          Out[(size_t)row * CDIM + gn] = v;
        }
      }
    }
  }
}

// ---------------- flash attention: barrier-free, direct-from-L2 ----------
// Each wave owns ONE 32-row q-tile; block = 4 consecutive tiles of one head
// (similar wave walls, shared L1 for K/V). NO LDS staging, NO barriers:
// K read as bf16x8 per-lane from global (L2-resident, 512KB/head, XCD-
// grouped); V read as ONE b128 per fragment from sigma-permuted Vt.
// Softmax/mask/MFMA bodies identical to HW-validated rounds 3-9.
__global__ __launch_bounds__(256, 4) void attn32g_kernel(
    const u16* __restrict__ Qb, const u16* __restrict__ Kb,
    const u16* __restrict__ Vt, u16* __restrict__ yb,
    const int* __restrict__ lengths) {
  __shared__ __attribute__((aligned(16))) u16 yts[4 * 32 * 72];  // epilogue only
  const int t = threadIdx.x, lane = t & 63, wid = t >> 6;
  const int l31 = lane & 31, hi = lane >> 5;
  const int wgid = blockIdx.x;               // 0..1023
  const int xcd = wgid & 7, slot = wgid >> 3;   // slot 0..127
  const int bh = xcd * 8 + (slot >> 4);      // 8 heads per XCD (L2 locality)
  const int grp = slot & 15;                 // 4-tile group within head
  const int b = bh >> 4, h = bh & (NH - 1);
  const int len = lengths[b];
  if (grp * 128 >= len) return;              // whole block inactive (uniform)
  const int q0w = (grp * 4 + wid) * 32;      // this wave's q-tile
  const bool act = q0w < len;
  const int qrow = q0w + l31;
  const u16* Qh = Qb + (size_t)bh * T_SEQ * DH;
  const u16* Kh = Kb + (size_t)bh * T_SEQ * DH;
  const u16* Vth = Vt + (size_t)bh * DH * T_SEQ;
  const float SC = 0.18033688011112042f;     // log2(e) / sqrt(64)
  const float THR = 44.3614195558365f;       // 8 / SC (raw-domain defer thr)

  if (act) {
    // per-wave Q B-fragments: B[n=q=l31][k=d=ks*16+hi*8+i]
    bf16x8 qf[4];
#pragma unroll
    for (int ks = 0; ks < 4; ks++)
      qf[ks] = *(const bf16x8*)&Qh[(size_t)qrow * DH + ks * 16 + hi * 8];

    f32x16 oacc[2];
    oacc[0] = (f32x16)0.f; oacc[1] = (f32x16)0.f;
    float mrun = NEGBIG, lrun = 0.f;

    const int ntiles = (q0w >> 6) + 1;       // KV tiles 0..q0w+31 inclusive

    for (int it = 0; it < ntiles; ++it) {
      const int kv0 = it << 6;
      const u16* Kt = Kh + (size_t)kv0 * DH;

      // S^T = K * Q^T, direct global K reads (A[row=key][k=d])
      f32x16 sacc[2];
      sacc[0] = (f32x16)0.f; sacc[1] = (f32x16)0.f;
      __builtin_amdgcn_s_setprio(1);
#pragma unroll
      for (int kb = 0; kb < 2; kb++)
#pragma unroll
        for (int ks = 0; ks < 4; ks++) {
          bf16x8 ak = *(const bf16x8*)&Kt[(size_t)(kb * 32 + l31) * DH + ks * 16 + hi * 8];
          sacc[kb] = __builtin_amdgcn_mfma_f32_32x32x16_bf16(
              ak, qf[ks], sacc[kb], 0, 0, 0);
        }
      __builtin_amdgcn_s_setprio(0);

      if ((kv0 + 63 > q0w) || (kv0 + 64 > len)) {   // mask (raw domain)
#pragma unroll
        for (int kb = 0; kb < 2; kb++)
#pragma unroll
          for (int r = 0; r < 16; r++) {
            int key = kv0 + kb * 32 + (r & 3) + 8 * (r >> 2) + 4 * hi;
            if (key > qrow || key >= len) sacc[kb][r] = NEGBIG;
          }
      }
      // tree max (depth 5) + cross-half shfl
      float tm[16];
#pragma unroll
      for (int r = 0; r < 16; r++) tm[r] = fmaxf(sacc[0][r], sacc[1][r]);
#pragma unroll
      for (int r = 0; r < 8; r++) tm[r] = fmaxf(tm[r], tm[r + 8]);
#pragma unroll
      for (int r = 0; r < 4; r++) tm[r] = fmaxf(tm[r], tm[r + 4]);
      tm[0] = fmaxf(fmaxf(tm[0], tm[2]), fmaxf(tm[1], tm[3]));
      float mt = fmaxf(tm[0], __shfl_xor(tm[0], 32));

      if (!__all(mt <= mrun + THR)) {        // defer-max (T13)
        float mnew = fmaxf(mrun, mt);
        float fac = exp2f((mrun - mnew) * SC);
        mrun = mnew;
        lrun *= fac;
#pragma unroll
        for (int r = 0; r < 16; r++) { oacc[0][r] *= fac; oacc[1][r] *= fac; }
      }
      const float msc = mrun * SC;
#pragma unroll
      for (int kb = 0; kb < 2; kb++)
#pragma unroll
        for (int r = 0; r < 16; r++)
          sacc[kb][r] = exp2f(fmaf(sacc[kb][r], SC, -msc));
      float pt[16];
#pragma unroll
      for (int r = 0; r < 16; r++) pt[r] = sacc[0][r] + sacc[1][r];
#pragma unroll
      for (int r = 0; r < 8; r++) pt[r] += pt[r + 8];
#pragma unroll
      for (int r = 0; r < 4; r++) pt[r] += pt[r + 4];
      float ps = (pt[0] + pt[2]) + (pt[1] + pt[3]);
      ps += __shfl_xor(ps, 32);
      lrun += ps;

      // O^T += V^T * P^T. sigma-permuted Vt: one b128 per fragment delivers
      // k-slot i = key ks*16+(i&3)+8*(i>>2)+4hi, matching pb's reg order.
#pragma unroll
      for (int ks = 0; ks < 4; ks++) {
        const int kb = ks >> 1, rb = (ks & 1) * 8;
        uint32_t d0, d1, d2, d3;
        asm("v_cvt_pk_bf16_f32 %0, %1, %2" : "=v"(d0)
            : "v"(sacc[kb][rb + 0]), "v"(sacc[kb][rb + 1]));
        asm("v_cvt_pk_bf16_f32 %0, %1, %2" : "=v"(d1)
            : "v"(sacc[kb][rb + 2]), "v"(sacc[kb][rb + 3]));
        asm("v_cvt_pk_bf16_f32 %0, %1, %2" : "=v"(d2)
            : "v"(sacc[kb][rb + 4]), "v"(sacc[kb][rb + 5]));
        asm("v_cvt_pk_bf16_f32 %0, %1, %2" : "=v"(d3)
            : "v"(sacc[kb][rb + 6]), "v"(sacc[kb][rb + 7]));
        bf16x8 pb = __builtin_bit_cast(bf16x8, (u32x4){d0, d1, d2, d3});
        __builtin_amdgcn_s_setprio(1);
#pragma unroll
        for (int mb = 0; mb < 2; mb++) {
          bf16x8 av = *(const bf16x8*)&Vth[(size_t)(mb * 32 + l31) * T_SEQ +
                                           kv0 + ks * 16 + hi * 8];
          oacc[mb] = __builtin_amdgcn_mfma_f32_32x32x16_bf16(
              av, pb, oacc[mb], 0, 0, 0);
        }
        __builtin_amdgcn_s_setprio(0);
      }
    }

    // epilogue (per-wave region, no cross-wave sync needed)
    u16* yt = yts + wid * (32 * 72);
    const float inv = (lrun > 0.f) ? 1.f / lrun : 0.f;
#pragma unroll
    for (int mb = 0; mb < 2; mb++)
#pragma unroll
      for (int r = 0; r < 16; r += 2) {
        int d = mb * 32 + (r & 3) + 8 * (r >> 2) + 4 * hi;
        float a0 = oacc[mb][r] * inv, a1 = oacc[mb][r + 1] * inv;
        uint32_t pw;
        asm("v_cvt_pk_bf16_f32 %0, %1, %2" : "=v"(pw) : "v"(a0), "v"(a1));
        *(uint32_t*)&yt[l31 * 72 + d] = pw;
      }
    asm volatile("s_waitcnt lgkmcnt(0)" ::: "memory");
    __builtin_amdgcn_sched_barrier(0);
#pragma unroll
    for (int pass = 0; pass < 4; pass++) {
      int rowq = pass * 8 + (lane >> 3);
      int col8 = (lane & 7) * 8;
      u16x8 v = *(const u16x8*)&yt[rowq * 72 + col8];
      *(u16x8*)&yb[((size_t)b * T_SEQ + q0w + rowq) * CDIM + h * DH + col8] = v;
    }
  }
}

// ---------------- launch ----------------
extern "C" void kernel_launch(void* const* d_in, const int* in_sizes, int n_in,
                              void* d_out, int out_size, void* d_ws, size_t ws_size,
                              hipStream_t stream) {
  const float* x  = (const float*)d_in[0];
  const void*  mask = d_in[1];
  const float* Wa = (const float*)d_in[2];
  const float* ba = (const float*)d_in[3];
  const float* Wp = (const float*)d_in[4];
  const float* bp = (const float*)d_in[5];
  float* out = (float*)d_out;

  char* w = (char*)d_ws;
  u16* xb  = (u16*)w; w += (size_t)MROWS * CDIM * 2;   // 16 MB (reused as yb)
  u16* WaT = (u16*)w; w += (size_t)N3 * CDIM * 2;      // 6 MB
  u16* WpT = (u16*)w; w += (size_t)CDIM * CDIM * 2;    // 2 MB
  u16* Qb  = (u16*)w; w += (size_t)MROWS * CDIM * 2;   // 16 MB
  u16* Kb  = (u16*)w; w += (size_t)MROWS * CDIM * 2;   // 16 MB
  u16* Vt  = (u16*)w; w += (size_t)MROWS * CDIM * 2;   // 16 MB  [b,h,d,t']
  int* lengths = (int*)w;                               // 16 B
  u16* yb = xb;  // alias: xb dead after QKV GEMM

  cvt_f32_bf16<<<(MROWS * CDIM / 4 + 255) / 256, 256, 0, stream>>>(x, xb, MROWS * CDIM);
  wt_tiled<<<dim3(N3 / 64, CDIM / 64), 256, 0, stream>>>(Wa, WaT, CDIM, N3);
  wt_tiled<<<dim3(CDIM / 64, CDIM / 64), 256, 0, stream>>>(Wp, WpT, CDIM, CDIM);
  len_kernel<<<BATCH, 256, 0, stream>>>(mask, lengths);

  gemm_bf16<0><<<dim3(N3 / 128, MROWS / 128), 256, 0, stream>>>(
      xb, WaT, ba, Qb, Kb, Vt, nullptr, nullptr, MROWS, N3, CDIM);

  attn32g_kernel<<<dim3(1024), 256, 0, stream>>>(
      Qb, Kb, Vt, yb, lengths);

  gemm_bf16<1><<<dim3(CDIM / 128, MROWS / 128), 256, 0, stream>>>(
      yb, WpT, bp, nullptr, nullptr, nullptr, out, lengths, MROWS, CDIM, CDIM);
}

// Round 11
// 298.839 us; speedup vs baseline: 1.1573x; 1.1573x over previous
//
#include <hip/hip_runtime.h>
#include <stdint.h>

// Problem constants (B=4, T=2048, C=1024, H=16, D=64)
#define T_SEQ 2048
#define CDIM  1024
#define NH    16
#define DH    64
#define BATCH 4
#define MROWS (BATCH * T_SEQ)   // 8192
#define N3    (3 * CDIM)        // 3072
#define NEGBIG -1e30f

typedef unsigned short u16;
typedef __attribute__((ext_vector_type(8))) __bf16 bf16x8;
typedef __attribute__((ext_vector_type(8))) unsigned short u16x8;
typedef __attribute__((ext_vector_type(4))) float f32x4;
typedef __attribute__((ext_vector_type(16))) float f32x16;
typedef __attribute__((ext_vector_type(4))) unsigned int u32x4;

__device__ inline u16 f2bf(float f) {
  uint32_t u = __builtin_bit_cast(uint32_t, f);
  u += 0x7FFFu + ((u >> 16) & 1u);   // RNE; inputs finite
  return (u16)(u >> 16);
}

// async global->LDS, 16B per lane; LDS dest = wave-uniform base + lane*16
__device__ inline void gld_lds16(const void* g, void* l) {
  __builtin_amdgcn_global_load_lds(
      (const __attribute__((address_space(1))) void*)g,
      (__attribute__((address_space(3))) void*)l, 16, 0, 0);
}

// ---------------- aux kernels ----------------

__global__ __launch_bounds__(256) void cvt_f32_bf16(
    const float* __restrict__ in, u16* __restrict__ out, int n) {
  int i = (blockIdx.x * 256 + threadIdx.x) * 4;
  if (i >= n) return;
  float4 v = *(const float4*)&in[i];
  ushort4 o; o.x = f2bf(v.x); o.y = f2bf(v.y); o.z = f2bf(v.z); o.w = f2bf(v.w);
  *(ushort4*)&out[i] = o;
}

// W [K][N] fp32 -> WT [N][K] bf16, LDS-tiled (coalesced both sides)
__global__ __launch_bounds__(256) void wt_tiled(
    const float* __restrict__ W, u16* __restrict__ WT, int K, int N) {
  __shared__ float tile[64][65];
  const int k0 = blockIdx.y * 64, n0 = blockIdx.x * 64;
  const int t = threadIdx.x, cr = t >> 6, cc = t & 63;
#pragma unroll
  for (int i = 0; i < 16; i++) {
    int r = i * 4 + cr;
    tile[r][cc] = W[(size_t)(k0 + r) * N + n0 + cc];
  }
  __syncthreads();
#pragma unroll
  for (int i = 0; i < 16; i++) {
    int r = i * 4 + cr;  // output row (n)
    WT[(size_t)(n0 + r) * K + k0 + cc] = f2bf(tile[cc][r]);
  }
}

// lengths[b] = count of non-padded rows; auto-detect int32 vs byte mask.
__global__ __launch_bounds__(256) void len_kernel(
    const void* __restrict__ maskp, int* __restrict__ lengths) {
  __shared__ int flag;
  __shared__ int red[256];
  const int t = threadIdx.x, b = blockIdx.x;
  if (t == 0) flag = 0;
  __syncthreads();
  const uint32_t* mw = (const uint32_t*)maskp;
  int f = 0;
  for (int i = t; i < 2048; i += 256) f |= (mw[i] > 1u) ? 1 : 0;
  if (f) atomicOr(&flag, 1);
  __syncthreads();
  int cnt = 0;
  if (flag) {
    const uint8_t* mb = (const uint8_t*)maskp;
    for (int i = t; i < T_SEQ; i += 256) cnt += (mb[(size_t)b * T_SEQ + i] == 0);
  } else {
    const int* mi = (const int*)maskp;
    for (int i = t; i < T_SEQ; i += 256) cnt += (mi[(size_t)b * T_SEQ + i] == 0);
  }
  red[t] = cnt;
  __syncthreads();
  for (int s = 128; s > 0; s >>= 1) {
    if (t < s) red[t] += red[t + s];
    __syncthreads();
  }
  if (t == 0) lengths[b] = red[0];
}

// ---------------- GEMM: C[M,N] = A[M,K] * Bt[N,K]^T + bias ----------------
// 128x128 tile, BK=64, 4 waves, mfma_f32_16x16x32_bf16, XOR-swizzled LDS.
// MODE 0: n<2048 -> scatter Q/K [b,h,t,d]; n>=2048 -> V transposed to
//         Vt [b,h,d,t'] (t' sigma-permuted: swap bits 2,3 of t&15, so attn's
//         PV reads one contiguous b128 per fragment). MODE 1: fp32 out.
template <int MODE>
__global__ __launch_bounds__(256, 2) void gemm_bf16(
    const u16* __restrict__ A, const u16* __restrict__ Bt,
    const float* __restrict__ bias,
    u16* __restrict__ Qb, u16* __restrict__ Kb, u16* __restrict__ Vt,
    float* __restrict__ Out, const int* __restrict__ lengths,
    int Mdim, int Ndim, int Kdim) {
  __shared__ u16 SM[16384];           // As = SM[0:8192], Bs = SM[8192:16384]
  u16* As = SM;
  u16* Bs = SM + 8192;
  const int t = threadIdx.x;
  const int lane = t & 63, wid = t >> 6;
  const int wr = wid >> 1, wc = wid & 1;
  const int r16 = lane & 15, kg = lane >> 4;
  const int m0 = blockIdx.y * 128, n0 = blockIdx.x * 128;

  f32x4 acc[4][4];
#pragma unroll
  for (int i = 0; i < 4; i++)
#pragma unroll
    for (int j = 0; j < 4; j++) acc[i][j] = (f32x4){0.f, 0.f, 0.f, 0.f};

  for (int k0 = 0; k0 < Kdim; k0 += 64) {
#pragma unroll
    for (int i = 0; i < 4; i++) {
      int idx = i * 256 + t;           // 0..1023
      int row = idx >> 3;              // 0..127
      int chunk = idx & 7;
      int colel = (chunk * 8) ^ ((row & 7) << 3);
      gld_lds16(&A[(size_t)(m0 + row) * Kdim + k0 + colel], &As[idx * 8]);
      gld_lds16(&Bt[(size_t)(n0 + row) * Kdim + k0 + colel], &Bs[idx * 8]);
    }
    __syncthreads();

#pragma unroll
    for (int s = 0; s < 2; s++) {
      bf16x8 af[4], bfr[4];
#pragma unroll
      for (int m = 0; m < 4; m++) {
        int row = wr * 64 + m * 16 + r16;
        int colel = (s * 32 + kg * 8) ^ ((row & 7) << 3);
        af[m] = *(const bf16x8*)&As[row * 64 + colel];
      }
#pragma unroll
      for (int n = 0; n < 4; n++) {
        int row = wc * 64 + n * 16 + r16;
        int colel = (s * 32 + kg * 8) ^ ((row & 7) << 3);
        bfr[n] = *(const bf16x8*)&Bs[row * 64 + colel];
      }
#pragma unroll
      for (int m = 0; m < 4; m++)
#pragma unroll
        for (int n = 0; n < 4; n++)
          acc[m][n] = __builtin_amdgcn_mfma_f32_16x16x32_bf16(
              af[m], bfr[n], acc[m][n], 0, 0, 0);
    }
    __syncthreads();
  }

  // epilogue: C/D layout col=lane&15, row=(lane>>4)*4+reg
  if (MODE == 0 && n0 >= 2048) {
    // V block -> transpose via LDS, write Vt[b,h,d,t'] (t' sigma-permuted)
    u16* Tt = SM;  // [128][128], chunk-swizzled
#pragma unroll
    for (int m = 0; m < 4; m++)
#pragma unroll
      for (int n = 0; n < 4; n++) {
        int ln = wc * 64 + n * 16 + r16;     // local n (d-ish)
        float bv = bias[n0 + ln];
#pragma unroll
        for (int reg = 0; reg < 4; reg++) {
          int lm = wr * 64 + m * 16 + kg * 4 + reg;  // local m (t)
          Tt[ln * 128 + (lm ^ ((ln & 7) << 3))] = f2bf(acc[m][n][reg] + bv);
        }
      }
    __syncthreads();
    const int b = m0 >> 11;
    const int tt0 = m0 & 2047;            // within-batch t offset
    const int cbase = n0 - 2048;
#pragma unroll
    for (int i = 0; i < 8; i++) {
      int u = i * 256 + t;
      int ln = u >> 4, ch = u & 15;
      u16x8 v = *(const u16x8*)&Tt[ln * 128 + ((ch * 8) ^ ((ln & 7) << 3))];
      int c = cbase + ln, hh = c >> 6, d = c & 63;
      size_t base = (((size_t)b * NH + hh) * DH + d) * T_SEQ;
      // sigma store: keys k0q..k0q+7 -> slots (swap bits 2,3 within t&15)
      int k0q = tt0 + ch * 8;
      int shift = (ch & 1) << 2;          // 0 (ch even) or 4 (ch odd)
      ushort4 qa; qa.x = (u16)v[0]; qa.y = (u16)v[1]; qa.z = (u16)v[2]; qa.w = (u16)v[3];
      ushort4 qb; qb.x = (u16)v[4]; qb.y = (u16)v[5]; qb.z = (u16)v[6]; qb.w = (u16)v[7];
      *(ushort4*)&Vt[base + k0q - shift] = qa;
      *(ushort4*)&Vt[base + k0q + 8 - shift] = qb;
    }
    return;
  }

#pragma unroll
  for (int m = 0; m < 4; m++) {
    int gmb = m0 + wr * 64 + m * 16 + kg * 4;
#pragma unroll
    for (int n = 0; n < 4; n++) {
      int gn = n0 + wc * 64 + n * 16 + r16;
      float bv = bias[gn];
#pragma unroll
      for (int reg = 0; reg < 4; reg++) {
        float v = acc[m][n][reg] + bv;
        int row = gmb + reg;           // = b*T + t
        int b = row >> 11, tt = row & 2047;
        if (MODE == 0) {
          int c = gn & 1023, h = c >> 6, d = c & 63;
          u16* dst = (gn < 1024) ? Qb : Kb;
          dst[((size_t)(b * NH + h) * T_SEQ + tt) * DH + d] = f2bf(v);
        } else {
          if (tt >= lengths[b]) v = 0.f;
          Out[(size_t)row * CDIM + gn] = v;
        }
      }
    }
  }
}

// ---------------- flash attention: barrier-free + REGISTER double-buffer --
// r10 structure (wave-owns-32-row-tile, direct global K, sigma-permuted Vt,
// no LDS/barriers in loop) + the fix for its measured failure (load latency
// exposed, VALU 14%): distance-1 REGISTER prefetch. Per iteration:
//   LOADV(it) issued first -> in flight across QK+softmax;
//   QK consumes kA (prefetched LAST iteration -> counted vmcnt, no stall);
//   LOADK(it+1)->kB issued right after kA's last use;
//   softmax VALU hides both; PV consumes V.
// Unrolled x2 with named kA/kB (static reg indexing, rule #20).
__global__ __launch_bounds__(256) void attn32r_kernel(
    const u16* __restrict__ Qb, const u16* __restrict__ Kb,
    const u16* __restrict__ Vt, u16* __restrict__ yb,
    const int* __restrict__ lengths) {
  __shared__ __attribute__((aligned(16))) u16 yts[4 * 32 * 72];  // epilogue only
  const int t = threadIdx.x, lane = t & 63, wid = t >> 6;
  const int l31 = lane & 31, hi = lane >> 5;
  const int wgid = blockIdx.x;               // 0..1023
  const int xcd = wgid & 7, slot = wgid >> 3;   // slot 0..127
  const int bh = xcd * 8 + (slot >> 4);      // 8 heads per XCD (L2 locality)
  const int grp = slot & 15;                 // 4-tile group within head
  const int b = bh >> 4, h = bh & (NH - 1);
  const int len = lengths[b];
  if (grp * 128 >= len) return;              // whole block inactive (uniform)
  const int q0w = (grp * 4 + wid) * 32;      // this wave's q-tile
  if (q0w >= len) return;                    // per-wave exit (no barriers used)
  const int qrow = q0w + l31;
  const u16* Qh = Qb + (size_t)bh * T_SEQ * DH;
  const u16* Kh = Kb + (size_t)bh * T_SEQ * DH;
  const u16* Vth = Vt + (size_t)bh * DH * T_SEQ;
  const float SC = 0.18033688011112042f;     // log2(e) / sqrt(64)
  const float THR = 44.3614195558365f;       // 8 / SC (raw-domain defer thr)

  // per-wave Q B-fragments: B[n=q=l31][k=d=ks*16+hi*8+i]
  bf16x8 qf[4];
#pragma unroll
  for (int ks = 0; ks < 4; ks++)
    qf[ks] = *(const bf16x8*)&Qh[(size_t)qrow * DH + ks * 16 + hi * 8];

  f32x16 oacc[2];
  oacc[0] = (f32x16)0.f; oacc[1] = (f32x16)0.f;
  float mrun = NEGBIG, lrun = 0.f;

  const int ntiles = (q0w >> 6) + 1;         // KV tiles 0..q0w+31 inclusive

  auto LOADK = [&](bf16x8* kf, int kv0) {    // 8 x b128, key-major fragments
    const u16* Kt = Kh + (size_t)kv0 * DH;
#pragma unroll
    for (int kb = 0; kb < 2; kb++)
#pragma unroll
      for (int ks = 0; ks < 4; ks++)
        kf[kb * 4 + ks] =
            *(const bf16x8*)&Kt[(size_t)(kb * 32 + l31) * DH + ks * 16 + hi * 8];
  };
  auto LOADV = [&](bf16x8* vf, int kv0) {    // 8 x b128 from sigma-permuted Vt
#pragma unroll
    for (int ks = 0; ks < 4; ks++)
#pragma unroll
      for (int mb = 0; mb < 2; mb++)
        vf[ks * 2 + mb] = *(const bf16x8*)&Vth[(size_t)(mb * 32 + l31) * T_SEQ +
                                               kv0 + ks * 16 + hi * 8];
  };

  // one flash step; kf = K fragments (in regs), vf = V fragments (in regs)
  auto FLASH = [&](const bf16x8* kf, const bf16x8* vf, int kv0) {
    f32x16 sacc[2];
    sacc[0] = (f32x16)0.f; sacc[1] = (f32x16)0.f;
    __builtin_amdgcn_s_setprio(1);
#pragma unroll
    for (int kb = 0; kb < 2; kb++)
#pragma unroll
      for (int ks = 0; ks < 4; ks++)
        sacc[kb] = __builtin_amdgcn_mfma_f32_32x32x16_bf16(
            kf[kb * 4 + ks], qf[ks], sacc[kb], 0, 0, 0);
    __builtin_amdgcn_s_setprio(0);

    if ((kv0 + 63 > q0w) || (kv0 + 64 > len)) {   // mask (raw domain)
#pragma unroll
      for (int kb = 0; kb < 2; kb++)
#pragma unroll
        for (int r = 0; r < 16; r++) {
          int key = kv0 + kb * 32 + (r & 3) + 8 * (r >> 2) + 4 * hi;
          if (key > qrow || key >= len) sacc[kb][r] = NEGBIG;
        }
    }
    // tree max (depth 5) + cross-half shfl
    float tm[16];
#pragma unroll
    for (int r = 0; r < 16; r++) tm[r] = fmaxf(sacc[0][r], sacc[1][r]);
#pragma unroll
    for (int r = 0; r < 8; r++) tm[r] = fmaxf(tm[r], tm[r + 8]);
#pragma unroll
    for (int r = 0; r < 4; r++) tm[r] = fmaxf(tm[r], tm[r + 4]);
    tm[0] = fmaxf(fmaxf(tm[0], tm[2]), fmaxf(tm[1], tm[3]));
    float mt = fmaxf(tm[0], __shfl_xor(tm[0], 32));

    if (!__all(mt <= mrun + THR)) {          // defer-max (T13)
      float mnew = fmaxf(mrun, mt);
      float fac = exp2f((mrun - mnew) * SC);
      mrun = mnew;
      lrun *= fac;
#pragma unroll
      for (int r = 0; r < 16; r++) { oacc[0][r] *= fac; oacc[1][r] *= fac; }
    }
    const float msc = mrun * SC;
#pragma unroll
    for (int kb = 0; kb < 2; kb++)
#pragma unroll
      for (int r = 0; r < 16; r++)
        sacc[kb][r] = exp2f(fmaf(sacc[kb][r], SC, -msc));
    float pt[16];
#pragma unroll
    for (int r = 0; r < 16; r++) pt[r] = sacc[0][r] + sacc[1][r];
#pragma unroll
    for (int r = 0; r < 8; r++) pt[r] += pt[r + 8];
#pragma unroll
    for (int r = 0; r < 4; r++) pt[r] += pt[r + 4];
    float ps = (pt[0] + pt[2]) + (pt[1] + pt[3]);
    ps += __shfl_xor(ps, 32);
    lrun += ps;

    // O^T += V^T * P^T (slot-permuted; vf[ks*2+mb] matches pb's reg order)
#pragma unroll
    for (int ks = 0; ks < 4; ks++) {
      const int kb = ks >> 1, rb = (ks & 1) * 8;
      uint32_t d0, d1, d2, d3;
      asm("v_cvt_pk_bf16_f32 %0, %1, %2" : "=v"(d0)
          : "v"(sacc[kb][rb + 0]), "v"(sacc[kb][rb + 1]));
      asm("v_cvt_pk_bf16_f32 %0, %1, %2" : "=v"(d1)
          : "v"(sacc[kb][rb + 2]), "v"(sacc[kb][rb + 3]));
      asm("v_cvt_pk_bf16_f32 %0, %1, %2" : "=v"(d2)
          : "v"(sacc[kb][rb + 4]), "v"(sacc[kb][rb + 5]));
      asm("v_cvt_pk_bf16_f32 %0, %1, %2" : "=v"(d3)
          : "v"(sacc[kb][rb + 6]), "v"(sacc[kb][rb + 7]));
      bf16x8 pb = __builtin_bit_cast(bf16x8, (u32x4){d0, d1, d2, d3});
      __builtin_amdgcn_s_setprio(1);
#pragma unroll
      for (int mb = 0; mb < 2; mb++)
        oacc[mb] = __builtin_amdgcn_mfma_f32_32x32x16_bf16(
            vf[ks * 2 + mb], pb, oacc[mb], 0, 0, 0);
      __builtin_amdgcn_s_setprio(0);
    }
  };

  // software pipeline: kA prefetched for current, kB for next; V per-iter
  bf16x8 kA[8], kB[8], vv[8];
  LOADK(kA, 0);
  for (int it = 0; it < ntiles; it += 2) {
    // even iteration: consume kA, prefetch kB
    LOADV(vv, it << 6);
    if (it + 1 < ntiles) LOADK(kB, (it + 1) << 6);
    FLASH(kA, vv, it << 6);
    if (it + 1 < ntiles) {
      // odd iteration: consume kB, prefetch kA
      LOADV(vv, (it + 1) << 6);
      if (it + 2 < ntiles) LOADK(kA, (it + 2) << 6);
      FLASH(kB, vv, (it + 1) << 6);
    }
  }

  // epilogue (per-wave region, no cross-wave sync needed)
  u16* yt = yts + wid * (32 * 72);
  const float inv = (lrun > 0.f) ? 1.f / lrun : 0.f;
#pragma unroll
  for (int mb = 0; mb < 2; mb++)
#pragma unroll
    for (int r = 0; r < 16; r += 2) {
      int d = mb * 32 + (r & 3) + 8 * (r >> 2) + 4 * hi;
      float a0 = oacc[mb][r] * inv, a1 = oacc[mb][r + 1] * inv;
      uint32_t pw;
      asm("v_cvt_pk_bf16_f32 %0, %1, %2" : "=v"(pw) : "v"(a0), "v"(a1));
      *(uint32_t*)&yt[l31 * 72 + d] = pw;
    }
  asm volatile("s_waitcnt lgkmcnt(0)" ::: "memory");
  __builtin_amdgcn_sched_barrier(0);
#pragma unroll
  for (int pass = 0; pass < 4; pass++) {
    int rowq = pass * 8 + (lane >> 3);
    int col8 = (lane & 7) * 8;
    u16x8 v = *(const u16x8*)&yt[rowq * 72 + col8];
    *(u16x8*)&yb[((size_t)b * T_SEQ + q0w + rowq) * CDIM + h * DH + col8] = v;
  }
}

// ---------------- launch ----------------
extern "C" void kernel_launch(void* const* d_in, const int* in_sizes, int n_in,
                              void* d_out, int out_size, void* d_ws, size_t ws_size,
                              hipStream_t stream) {
  const float* x  = (const float*)d_in[0];
  const void*  mask = d_in[1];
  const float* Wa = (const float*)d_in[2];
  const float* ba = (const float*)d_in[3];
  const float* Wp = (const float*)d_in[4];
  const float* bp = (const float*)d_in[5];
  float* out = (float*)d_out;

  char* w = (char*)d_ws;
  u16* xb  = (u16*)w; w += (size_t)MROWS * CDIM * 2;   // 16 MB (reused as yb)
  u16* WaT = (u16*)w; w += (size_t)N3 * CDIM * 2;      // 6 MB
  u16* WpT = (u16*)w; w += (size_t)CDIM * CDIM * 2;    // 2 MB
  u16* Qb  = (u16*)w; w += (size_t)MROWS * CDIM * 2;   // 16 MB
  u16* Kb  = (u16*)w; w += (size_t)MROWS * CDIM * 2;   // 16 MB
  u16* Vt  = (u16*)w; w += (size_t)MROWS * CDIM * 2;   // 16 MB  [b,h,d,t']
  int* lengths = (int*)w;                               // 16 B
  u16* yb = xb;  // alias: xb dead after QKV GEMM

  cvt_f32_bf16<<<(MROWS * CDIM / 4 + 255) / 256, 256, 0, stream>>>(x, xb, MROWS * CDIM);
  wt_tiled<<<dim3(N3 / 64, CDIM / 64), 256, 0, stream>>>(Wa, WaT, CDIM, N3);
  wt_tiled<<<dim3(CDIM / 64, CDIM / 64), 256, 0, stream>>>(Wp, WpT, CDIM, CDIM);
  len_kernel<<<BATCH, 256, 0, stream>>>(mask, lengths);

  gemm_bf16<0><<<dim3(N3 / 128, MROWS / 128), 256, 0, stream>>>(
      xb, WaT, ba, Qb, Kb, Vt, nullptr, nullptr, MROWS, N3, CDIM);

  attn32r_kernel<<<dim3(1024), 256, 0, stream>>>(
      Qb, Kb, Vt, yb, lengths);

  gemm_bf16<1><<<dim3(CDIM / 128, MROWS / 128), 256, 0, stream>>>(
      yb, WpT, bp, nullptr, nullptr, nullptr, out, lengths, MROWS, CDIM, CDIM);
}

// Round 12
// 239.806 us; speedup vs baseline: 1.4423x; 1.2462x over previous
//
#include <hip/hip_runtime.h>
#include <stdint.h>

// Problem constants (B=4, T=2048, C=1024, H=16, D=64)
#define T_SEQ 2048
#define CDIM  1024
#define NH    16
#define DH    64
#define BATCH 4
#define MROWS (BATCH * T_SEQ)   // 8192
#define N3    (3 * CDIM)        // 3072
#define NEGBIG -1e30f

typedef unsigned short u16;
typedef __attribute__((ext_vector_type(8))) __bf16 bf16x8;
typedef __attribute__((ext_vector_type(4))) __bf16 bf16x4;
typedef __attribute__((ext_vector_type(8))) unsigned short u16x8;
typedef __attribute__((ext_vector_type(4))) float f32x4;
typedef __attribute__((ext_vector_type(16))) float f32x16;
typedef __attribute__((ext_vector_type(4))) unsigned int u32x4;

__device__ inline u16 f2bf(float f) {
  uint32_t u = __builtin_bit_cast(uint32_t, f);
  u += 0x7FFFu + ((u >> 16) & 1u);   // RNE; inputs finite
  return (u16)(u >> 16);
}

// async global->LDS, 16B per lane; LDS dest = wave-uniform base + lane*16
__device__ inline void gld_lds16(const void* g, void* l) {
  __builtin_amdgcn_global_load_lds(
      (const __attribute__((address_space(1))) void*)g,
      (__attribute__((address_space(3))) void*)l, 16, 0, 0);
}

// ---------------- aux kernels ----------------

__global__ __launch_bounds__(256) void cvt_f32_bf16(
    const float* __restrict__ in, u16* __restrict__ out, int n) {
  int i = (blockIdx.x * 256 + threadIdx.x) * 4;
  if (i >= n) return;
  float4 v = *(const float4*)&in[i];
  ushort4 o; o.x = f2bf(v.x); o.y = f2bf(v.y); o.z = f2bf(v.z); o.w = f2bf(v.w);
  *(ushort4*)&out[i] = o;
}

// W [K][N] fp32 -> WT [N][K] bf16, LDS-tiled (coalesced both sides)
__global__ __launch_bounds__(256) void wt_tiled(
    const float* __restrict__ W, u16* __restrict__ WT, int K, int N) {
  __shared__ float tile[64][65];
  const int k0 = blockIdx.y * 64, n0 = blockIdx.x * 64;
  const int t = threadIdx.x, cr = t >> 6, cc = t & 63;
#pragma unroll
  for (int i = 0; i < 16; i++) {
    int r = i * 4 + cr;
    tile[r][cc] = W[(size_t)(k0 + r) * N + n0 + cc];
  }
  __syncthreads();
#pragma unroll
  for (int i = 0; i < 16; i++) {
    int r = i * 4 + cr;  // output row (n)
    WT[(size_t)(n0 + r) * K + k0 + cc] = f2bf(tile[cc][r]);
  }
}

// lengths[b] = count of non-padded rows; auto-detect int32 vs byte mask.
__global__ __launch_bounds__(256) void len_kernel(
    const void* __restrict__ maskp, int* __restrict__ lengths) {
  __shared__ int flag;
  __shared__ int red[256];
  const int t = threadIdx.x, b = blockIdx.x;
  if (t == 0) flag = 0;
  __syncthreads();
  const uint32_t* mw = (const uint32_t*)maskp;
  int f = 0;
  for (int i = t; i < 2048; i += 256) f |= (mw[i] > 1u) ? 1 : 0;
  if (f) atomicOr(&flag, 1);
  __syncthreads();
  int cnt = 0;
  if (flag) {
    const uint8_t* mb = (const uint8_t*)maskp;
    for (int i = t; i < T_SEQ; i += 256) cnt += (mb[(size_t)b * T_SEQ + i] == 0);
  } else {
    const int* mi = (const int*)maskp;
    for (int i = t; i < T_SEQ; i += 256) cnt += (mi[(size_t)b * T_SEQ + i] == 0);
  }
  red[t] = cnt;
  __syncthreads();
  for (int s = 128; s > 0; s >>= 1) {
    if (t < s) red[t] += red[t + s];
    __syncthreads();
  }
  if (t == 0) lengths[b] = red[0];
}

// ---------------- GEMM: C[M,N] = A[M,K] * Bt[N,K]^T + bias ----------------
// 128x128 tile, BK=64, 4 waves, mfma_f32_16x16x32_bf16, XOR-swizzled LDS.
// MODE 0: n<2048 -> Q/K [b,h,t,d] via LDS bounce (16B stores; was 64 scalar
//         u16 stores/thread); n>=2048 -> V transposed to Vt [b,h,d,t] via
//         in-LDS 128x128 transpose (r7-proven). MODE 1: fp32 out + zeroing.
template <int MODE>
__global__ __launch_bounds__(256, 2) void gemm_bf16(
    const u16* __restrict__ A, const u16* __restrict__ Bt,
    const float* __restrict__ bias,
    u16* __restrict__ Qb, u16* __restrict__ Kb, u16* __restrict__ Vt,
    float* __restrict__ Out, const int* __restrict__ lengths,
    int Mdim, int Ndim, int Kdim) {
  __shared__ u16 SM[16384];           // As = SM[0:8192], Bs = SM[8192:16384]
  u16* As = SM;
  u16* Bs = SM + 8192;
  const int t = threadIdx.x;
  const int lane = t & 63, wid = t >> 6;
  const int wr = wid >> 1, wc = wid & 1;
  const int r16 = lane & 15, kg = lane >> 4;
  const int m0 = blockIdx.y * 128, n0 = blockIdx.x * 128;

  f32x4 acc[4][4];
#pragma unroll
  for (int i = 0; i < 4; i++)
#pragma unroll
    for (int j = 0; j < 4; j++) acc[i][j] = (f32x4){0.f, 0.f, 0.f, 0.f};

  for (int k0 = 0; k0 < Kdim; k0 += 64) {
#pragma unroll
    for (int i = 0; i < 4; i++) {
      int idx = i * 256 + t;           // 0..1023
      int row = idx >> 3;              // 0..127
      int chunk = idx & 7;
      int colel = (chunk * 8) ^ ((row & 7) << 3);
      gld_lds16(&A[(size_t)(m0 + row) * Kdim + k0 + colel], &As[idx * 8]);
      gld_lds16(&Bt[(size_t)(n0 + row) * Kdim + k0 + colel], &Bs[idx * 8]);
    }
    __syncthreads();

#pragma unroll
    for (int s = 0; s < 2; s++) {
      bf16x8 af[4], bfr[4];
#pragma unroll
      for (int m = 0; m < 4; m++) {
        int row = wr * 64 + m * 16 + r16;
        int colel = (s * 32 + kg * 8) ^ ((row & 7) << 3);
        af[m] = *(const bf16x8*)&As[row * 64 + colel];
      }
#pragma unroll
      for (int n = 0; n < 4; n++) {
        int row = wc * 64 + n * 16 + r16;
        int colel = (s * 32 + kg * 8) ^ ((row & 7) << 3);
        bfr[n] = *(const bf16x8*)&Bs[row * 64 + colel];
      }
#pragma unroll
      for (int m = 0; m < 4; m++)
#pragma unroll
        for (int n = 0; n < 4; n++)
          acc[m][n] = __builtin_amdgcn_mfma_f32_16x16x32_bf16(
              af[m], bfr[n], acc[m][n], 0, 0, 0);
    }
    __syncthreads();
  }

  // epilogue: C/D layout col=lane&15, row=(lane>>4)*4+reg
  if (MODE == 0) {
    const int b = m0 >> 11;
    const int tt0 = m0 & 2047;            // within-batch t offset
    if (n0 >= 2048) {
      // V block -> transpose via LDS, write Vt[b,h,d,t] coalesced (r7 path)
      u16* Tt = SM;  // [128][128], chunk-swizzled
#pragma unroll
      for (int m = 0; m < 4; m++)
#pragma unroll
        for (int n = 0; n < 4; n++) {
          int ln = wc * 64 + n * 16 + r16;     // local n (d-ish)
          float bv = bias[n0 + ln];
#pragma unroll
          for (int reg = 0; reg < 4; reg++) {
            int lm = wr * 64 + m * 16 + kg * 4 + reg;  // local m (t)
            Tt[ln * 128 + (lm ^ ((ln & 7) << 3))] = f2bf(acc[m][n][reg] + bv);
          }
        }
      __syncthreads();
      const int cbase = n0 - 2048;
#pragma unroll
      for (int i = 0; i < 8; i++) {
        int u = i * 256 + t;
        int ln = u >> 4, ch = u & 15;
        u16x8 v = *(const u16x8*)&Tt[ln * 128 + ((ch * 8) ^ ((ln & 7) << 3))];
        int c = cbase + ln, hh = c >> 6, d = c & 63;
        *(u16x8*)&Vt[(((size_t)b * NH + hh) * DH + d) * T_SEQ + tt0 + ch * 8] = v;
      }
    } else {
      // Q/K block -> LDS bounce (no transpose), 16B stores to [b,h,t,d]
      u16* Tt = SM;  // [128 t-rows][128 n-cols], col-swizzled per row
#pragma unroll
      for (int m = 0; m < 4; m++)
#pragma unroll
        for (int n = 0; n < 4; n++) {
          int ln = wc * 64 + n * 16 + r16;
          float bv = bias[n0 + ln];
#pragma unroll
          for (int reg = 0; reg < 4; reg++) {
            int lm = wr * 64 + m * 16 + kg * 4 + reg;
            Tt[lm * 128 + (ln ^ ((lm & 7) << 3))] = f2bf(acc[m][n][reg] + bv);
          }
        }
      __syncthreads();
      const int cb = n0 & 1023;             // block is entirely Q or K
      u16* dst = (n0 < 1024) ? Qb : Kb;
#pragma unroll
      for (int i = 0; i < 8; i++) {
        int u = i * 256 + t;
        int row = u >> 4, ch = u & 15;       // row = local t, ch = 8-col chunk
        u16x8 v = *(const u16x8*)&Tt[row * 128 + ((ch * 8) ^ ((row & 7) << 3))];
        int c = cb + ch * 8, hh = c >> 6, d = c & 63;
        *(u16x8*)&dst[((size_t)(b * NH + hh) * T_SEQ + tt0 + row) * DH + d] = v;
      }
    }
    return;
  }

#pragma unroll
  for (int m = 0; m < 4; m++) {
    int gmb = m0 + wr * 64 + m * 16 + kg * 4;
#pragma unroll
    for (int n = 0; n < 4; n++) {
      int gn = n0 + wc * 64 + n * 16 + r16;
      float bv = bias[gn];
#pragma unroll
      for (int reg = 0; reg < 4; reg++) {
        float v = acc[m][n][reg] + bv;
        int row = gmb + reg;           // = b*T + t
        int b = row >> 11, tt = row & 2047;
        if (tt >= lengths[b]) v = 0.f;
        Out[(size_t)row * CDIM + gn] = v;
      }
    }
  }
}

// ---------------- flash attention, length-aware pairs, ring-4 -----------
// ROUND-7-PROVEN kernel, byte-identical (131.7 us measured): ring-4 LDS,
// 1 barrier/iter, counted vmcnt(8/4/0), __shfl_xor softmax reduce,
// length-aware pairing {iq, nAct-1-iq}. (r8 XCD swizzle removed: it cut
// FETCH 96->22MB but cost +7us — attn is latency-bound, not BW-bound.)
__global__ __launch_bounds__(256) void attn32p_kernel(
    const u16* __restrict__ Qb, const u16* __restrict__ Kb,
    const u16* __restrict__ Vt, u16* __restrict__ yb,
    const int* __restrict__ lengths) {
  __shared__ __attribute__((aligned(16))) char smem[65536];  // 4 x (8K K + 8K V)
  const int t = threadIdx.x, lane = t & 63, wid = t >> 6;
  const int l31 = lane & 31, hi = lane >> 5;
  const int bh = blockIdx.y, b = bh >> 4, h = bh & (NH - 1);
  const int len = lengths[b];
  const int nAct = (len + 127) >> 7;         // active q-tiles (8..16)
  const int npairs = (nAct + 1) >> 1;
  const int iq = blockIdx.x;                 // 0..7
  if (iq >= npairs) return;                  // uniform, before any barrier
  const int q0L = iq * 128;
  const int q0H = (nAct - 1 - iq) * 128;
  const bool hiAct = q0H > q0L;              // middle tile pairs with itself
  const int q0Lw = q0L + wid * 32, q0Hw = q0H + wid * 32;
  const int qrowL = q0Lw + l31, qrowH = q0Hw + l31;
  const u16* Qh = Qb + (size_t)bh * T_SEQ * DH;
  const u16* Kh = Kb + (size_t)bh * T_SEQ * DH;
  const u16* Vth = Vt + (size_t)bh * DH * T_SEQ;
  const float SC = 0.18033688011112042f;     // log2(e) / sqrt(64)
  const float THR = 44.3614195558365f;       // 8 / SC (raw-domain defer thr)

  const int lenceil = (len + 63) & ~63;
  const int kvH = (q0H + 128 < lenceil) ? q0H + 128 : lenceil;
  const int kvL = (q0L + 128 < lenceil) ? q0L + 128 : lenceil;
  const int kv_end = hiAct ? kvH : kvL;
  const int ntiles = kv_end >> 6;            // >= 2 always

  // Q B-fragments for both tiles: B[n=q=l31][k=d=ks*16+hi*8+i]
  bf16x8 qfL[4], qfH[4];
#pragma unroll
  for (int ks = 0; ks < 4; ks++) {
    qfL[ks] = *(const bf16x8*)&Qh[(size_t)qrowL * DH + ks * 16 + hi * 8];
    qfH[ks] = *(const bf16x8*)&Qh[(size_t)qrowH * DH + ks * 16 + hi * 8];
  }

  f32x16 oaccL[2], oaccH[2];
  oaccL[0] = (f32x16)0.f; oaccL[1] = (f32x16)0.f;
  oaccH[0] = (f32x16)0.f; oaccH[1] = (f32x16)0.f;
  float mL = NEGBIG, lL = 0.f, mH = NEGBIG, lH = 0.f;

  // per-lane staging sources (running ptrs; K +8192B/tile, V +128B/tile)
  const int idx0 = t, idx1 = 256 + t;
  const int row0 = idx0 >> 3, ch0 = idx0 & 7;
  const int row1 = idx1 >> 3, ch1 = idx1 & 7;
  const int kc0 = (ch0 * 8) ^ ((row0 & 7) << 3);
  const int kc1 = (ch1 * 8) ^ ((row1 & 7) << 3);
  const char* kp0 = (const char*)Kh + ((size_t)row0 * DH + kc0) * 2;
  const char* kp1 = (const char*)Kh + ((size_t)row1 * DH + kc1) * 2;
  const char* vp0 = (const char*)Vth + ((size_t)row0 * T_SEQ + kc0) * 2;
  const char* vp1 = (const char*)Vth + ((size_t)row1 * T_SEQ + kc1) * 2;

  auto STAGE = [&](int bsel) {               // 4 vm-ops per thread
    char* base = smem + bsel * 16384;
    gld_lds16(kp0, base + idx0 * 16);
    gld_lds16(kp1, base + idx1 * 16);
    gld_lds16(vp0, base + 8192 + idx0 * 16);
    gld_lds16(vp1, base + 8192 + idx1 * 16);
    kp0 += 8192; kp1 += 8192; vp0 += 128; vp1 += 128;
  };

  // one flash step for one q-tile on the staged (Ks,Vts) KV tile
  auto FLASH = [&](const u16* Ks, const u16* Vts, int kv0, int q0w, int qrow,
                   bf16x8* qf, f32x16* oacc, float& mrun, float& lrun) {
    f32x16 sacc[2];
    sacc[0] = (f32x16)0.f; sacc[1] = (f32x16)0.f;
    __builtin_amdgcn_s_setprio(1);
#pragma unroll
    for (int kb = 0; kb < 2; kb++)
#pragma unroll
      for (int ks = 0; ks < 4; ks++) {
        int row = kb * 32 + l31;
        int col = (ks * 16 + hi * 8) ^ ((row & 7) << 3);
        bf16x8 ak = *(const bf16x8*)&Ks[row * 64 + col];
        sacc[kb] = __builtin_amdgcn_mfma_f32_32x32x16_bf16(
            ak, qf[ks], sacc[kb], 0, 0, 0);
      }
    __builtin_amdgcn_s_setprio(0);

    if ((kv0 + 63 > q0w) || (kv0 + 64 > len)) {   // mask (raw domain)
#pragma unroll
      for (int kb = 0; kb < 2; kb++)
#pragma unroll
        for (int r = 0; r < 16; r++) {
          int key = kv0 + kb * 32 + (r & 3) + 8 * (r >> 2) + 4 * hi;
          if (key > qrow || key >= len) sacc[kb][r] = NEGBIG;
        }
    }
    // tree max (depth 5) + cross-half shfl
    float tm[16];
#pragma unroll
    for (int r = 0; r < 16; r++) tm[r] = fmaxf(sacc[0][r], sacc[1][r]);
#pragma unroll
    for (int r = 0; r < 8; r++) tm[r] = fmaxf(tm[r], tm[r + 8]);
#pragma unroll
    for (int r = 0; r < 4; r++) tm[r] = fmaxf(tm[r], tm[r + 4]);
    tm[0] = fmaxf(fmaxf(tm[0], tm[2]), fmaxf(tm[1], tm[3]));
    float mt = fmaxf(tm[0], __shfl_xor(tm[0], 32));

    if (!__all(mt <= mrun + THR)) {          // defer-max (T13)
      float mnew = fmaxf(mrun, mt);
      float fac = exp2f((mrun - mnew) * SC);
      mrun = mnew;
      lrun *= fac;
#pragma unroll
      for (int r = 0; r < 16; r++) { oacc[0][r] *= fac; oacc[1][r] *= fac; }
    }
    const float msc = mrun * SC;
#pragma unroll
    for (int kb = 0; kb < 2; kb++)
#pragma unroll
      for (int r = 0; r < 16; r++)
        sacc[kb][r] = exp2f(fmaf(sacc[kb][r], SC, -msc));
    float pt[16];
#pragma unroll
    for (int r = 0; r < 16; r++) pt[r] = sacc[0][r] + sacc[1][r];
#pragma unroll
    for (int r = 0; r < 8; r++) pt[r] += pt[r + 8];
#pragma unroll
    for (int r = 0; r < 4; r++) pt[r] += pt[r + 4];
    float ps = (pt[0] + pt[2]) + (pt[1] + pt[3]);
    ps += __shfl_xor(ps, 32);
    lrun += ps;

    // O^T += V^T * P^T (slot-permuted, zero cross-lane traffic)
#pragma unroll
    for (int ks = 0; ks < 4; ks++) {
      const int kb = ks >> 1, rb = (ks & 1) * 8;
      uint32_t d0, d1, d2, d3;
      asm("v_cvt_pk_bf16_f32 %0, %1, %2" : "=v"(d0)
          : "v"(sacc[kb][rb + 0]), "v"(sacc[kb][rb + 1]));
      asm("v_cvt_pk_bf16_f32 %0, %1, %2" : "=v"(d1)
          : "v"(sacc[kb][rb + 2]), "v"(sacc[kb][rb + 3]));
      asm("v_cvt_pk_bf16_f32 %0, %1, %2" : "=v"(d2)
          : "v"(sacc[kb][rb + 4]), "v"(sacc[kb][rb + 5]));
      asm("v_cvt_pk_bf16_f32 %0, %1, %2" : "=v"(d3)
          : "v"(sacc[kb][rb + 6]), "v"(sacc[kb][rb + 7]));
      bf16x8 pb = __builtin_bit_cast(bf16x8, (u32x4){d0, d1, d2, d3});
      __builtin_amdgcn_s_setprio(1);
#pragma unroll
      for (int mb = 0; mb < 2; mb++) {
        int row = mb * 32 + l31;
        int sw = (row & 7);
        bf16x4 v1 = *(const bf16x4*)&Vts[row * 64 + ((2 * ks) ^ sw) * 8 + 4 * hi];
        bf16x4 v2 = *(const bf16x4*)&Vts[row * 64 + ((2 * ks + 1) ^ sw) * 8 + 4 * hi];
        bf16x8 av;
#pragma unroll
        for (int j = 0; j < 4; j++) { av[j] = v1[j]; av[4 + j] = v2[j]; }
        oacc[mb] = __builtin_amdgcn_mfma_f32_32x32x16_bf16(
            av, pb, oacc[mb], 0, 0, 0);
      }
      __builtin_amdgcn_s_setprio(0);
    }
  };

  // ring-4 pipeline: S_k issued at iter k-2; one barrier per iter
  STAGE(0); STAGE(1);
  for (int it = 0; it < ntiles; ++it) {
    if (it + 2 < ntiles) STAGE((it + 2) & 3);
    const int r = ntiles - 1 - it;
    if (r >= 2)      asm volatile("s_waitcnt vmcnt(8)" ::: "memory");
    else if (r == 1) asm volatile("s_waitcnt vmcnt(4)" ::: "memory");
    else             asm volatile("s_waitcnt vmcnt(0)" ::: "memory");
    __builtin_amdgcn_s_barrier();
    __builtin_amdgcn_sched_barrier(0);

    const u16* Ks  = (const u16*)(smem + (it & 3) * 16384);
    const u16* Vts = (const u16*)(smem + (it & 3) * 16384 + 8192);
    const int kv0 = it << 6;
    if (hiAct && kv0 <= q0Hw + 31)
      FLASH(Ks, Vts, kv0, q0Hw, qrowH, qfH, oaccH, mH, lH);
    if (kv0 <= q0Lw + 31)
      FLASH(Ks, Vts, kv0, q0Lw, qrowL, qfL, oaccL, mL, lL);
  }
  __syncthreads();  // all compute done before smem reuse as epilogue buffer

  // epilogue: O^T regs -> per-wave LDS [32 q][72 d] -> coalesced global
  u16* yt = (u16*)smem + wid * (32 * 72);
  auto EPI = [&](f32x16* oacc, float lrun, int q0w) {
    const float inv = (lrun > 0.f) ? 1.f / lrun : 0.f;
#pragma unroll
    for (int mb = 0; mb < 2; mb++)
#pragma unroll
      for (int r = 0; r < 16; r += 2) {
        int d = mb * 32 + (r & 3) + 8 * (r >> 2) + 4 * hi;
        float a0 = oacc[mb][r] * inv, a1 = oacc[mb][r + 1] * inv;
        uint32_t pw;
        asm("v_cvt_pk_bf16_f32 %0, %1, %2" : "=v"(pw) : "v"(a0), "v"(a1));
        *(uint32_t*)&yt[l31 * 72 + d] = pw;
      }
    asm volatile("s_waitcnt lgkmcnt(0)" ::: "memory");
    __builtin_amdgcn_sched_barrier(0);
#pragma unroll
    for (int pass = 0; pass < 4; pass++) {
      int rowq = pass * 8 + (lane >> 3);
      int col8 = (lane & 7) * 8;
      u16x8 v = *(const u16x8*)&yt[rowq * 72 + col8];
      *(u16x8*)&yb[((size_t)b * T_SEQ + q0w + rowq) * CDIM + h * DH + col8] = v;
    }
    asm volatile("s_waitcnt lgkmcnt(0)" ::: "memory");
    __builtin_amdgcn_sched_barrier(0);
  };
  EPI(oaccL, lL, q0Lw);
  if (hiAct) EPI(oaccH, lH, q0Hw);
}

// ---------------- launch ----------------
extern "C" void kernel_launch(void* const* d_in, const int* in_sizes, int n_in,
                              void* d_out, int out_size, void* d_ws, size_t ws_size,
                              hipStream_t stream) {
  const float* x  = (const float*)d_in[0];
  const void*  mask = d_in[1];
  const float* Wa = (const float*)d_in[2];
  const float* ba = (const float*)d_in[3];
  const float* Wp = (const float*)d_in[4];
  const float* bp = (const float*)d_in[5];
  float* out = (float*)d_out;

  char* w = (char*)d_ws;
  u16* xb  = (u16*)w; w += (size_t)MROWS * CDIM * 2;   // 16 MB (reused as yb)
  u16* WaT = (u16*)w; w += (size_t)N3 * CDIM * 2;      // 6 MB
  u16* WpT = (u16*)w; w += (size_t)CDIM * CDIM * 2;    // 2 MB
  u16* Qb  = (u16*)w; w += (size_t)MROWS * CDIM * 2;   // 16 MB
  u16* Kb  = (u16*)w; w += (size_t)MROWS * CDIM * 2;   // 16 MB
  u16* Vt  = (u16*)w; w += (size_t)MROWS * CDIM * 2;   // 16 MB  [b,h,d,t]
  int* lengths = (int*)w;                               // 16 B
  u16* yb = xb;  // alias: xb dead after QKV GEMM

  cvt_f32_bf16<<<(MROWS * CDIM / 4 + 255) / 256, 256, 0, stream>>>(x, xb, MROWS * CDIM);
  wt_tiled<<<dim3(N3 / 64, CDIM / 64), 256, 0, stream>>>(Wa, WaT, CDIM, N3);
  wt_tiled<<<dim3(CDIM / 64, CDIM / 64), 256, 0, stream>>>(Wp, WpT, CDIM, CDIM);
  len_kernel<<<BATCH, 256, 0, stream>>>(mask, lengths);

  gemm_bf16<0><<<dim3(N3 / 128, MROWS / 128), 256, 0, stream>>>(
      xb, WaT, ba, Qb, Kb, Vt, nullptr, nullptr, MROWS, N3, CDIM);

  attn32p_kernel<<<dim3(8, BATCH * NH), 256, 0, stream>>>(
      Qb, Kb, Vt, yb, lengths);

  gemm_bf16<1><<<dim3(CDIM / 128, MROWS / 128), 256, 0, stream>>>(
      yb, WpT, bp, nullptr, nullptr, nullptr, out, lengths, MROWS, CDIM, CDIM);
}

// Round 13
// 229.861 us; speedup vs baseline: 1.5047x; 1.0433x over previous
//
#include <hip/hip_runtime.h>
#include <stdint.h>

// Problem constants (B=4, T=2048, C=1024, H=16, D=64)
#define T_SEQ 2048
#define CDIM  1024
#define NH    16
#define DH    64
#define BATCH 4
#define MROWS (BATCH * T_SEQ)   // 8192
#define N3    (3 * CDIM)        // 3072
#define NEGBIG -1e30f

typedef unsigned short u16;
typedef __attribute__((ext_vector_type(8))) __bf16 bf16x8;
typedef __attribute__((ext_vector_type(4))) __bf16 bf16x4;
typedef __attribute__((ext_vector_type(8))) unsigned short u16x8;
typedef __attribute__((ext_vector_type(4))) float f32x4;
typedef __attribute__((ext_vector_type(16))) float f32x16;
typedef __attribute__((ext_vector_type(4))) unsigned int u32x4;

__device__ inline u16 f2bf(float f) {
  uint32_t u = __builtin_bit_cast(uint32_t, f);
  u += 0x7FFFu + ((u >> 16) & 1u);   // RNE; inputs finite
  return (u16)(u >> 16);
}

// async global->LDS, 16B per lane; LDS dest = wave-uniform base + lane*16
__device__ inline void gld_lds16(const void* g, void* l) {
  __builtin_amdgcn_global_load_lds(
      (const __attribute__((address_space(1))) void*)g,
      (__attribute__((address_space(3))) void*)l, 16, 0, 0);
}

// ---------------- aux kernels ----------------

__global__ __launch_bounds__(256) void cvt_f32_bf16(
    const float* __restrict__ in, u16* __restrict__ out, int n) {
  int i = (blockIdx.x * 256 + threadIdx.x) * 4;
  if (i >= n) return;
  float4 v = *(const float4*)&in[i];
  ushort4 o; o.x = f2bf(v.x); o.y = f2bf(v.y); o.z = f2bf(v.z); o.w = f2bf(v.w);
  *(ushort4*)&out[i] = o;
}

// W [K][N] fp32 -> WT [N][K] bf16, LDS-tiled (coalesced both sides)
__global__ __launch_bounds__(256) void wt_tiled(
    const float* __restrict__ W, u16* __restrict__ WT, int K, int N) {
  __shared__ float tile[64][65];
  const int k0 = blockIdx.y * 64, n0 = blockIdx.x * 64;
  const int t = threadIdx.x, cr = t >> 6, cc = t & 63;
#pragma unroll
  for (int i = 0; i < 16; i++) {
    int r = i * 4 + cr;
    tile[r][cc] = W[(size_t)(k0 + r) * N + n0 + cc];
  }
  __syncthreads();
#pragma unroll
  for (int i = 0; i < 16; i++) {
    int r = i * 4 + cr;  // output row (n)
    WT[(size_t)(n0 + r) * K + k0 + cc] = f2bf(tile[cc][r]);
  }
}

// lengths[b] = count of non-padded rows; auto-detect int32 vs byte mask.
__global__ __launch_bounds__(256) void len_kernel(
    const void* __restrict__ maskp, int* __restrict__ lengths) {
  __shared__ int flag;
  __shared__ int red[256];
  const int t = threadIdx.x, b = blockIdx.x;
  if (t == 0) flag = 0;
  __syncthreads();
  const uint32_t* mw = (const uint32_t*)maskp;
  int f = 0;
  for (int i = t; i < 2048; i += 256) f |= (mw[i] > 1u) ? 1 : 0;
  if (f) atomicOr(&flag, 1);
  __syncthreads();
  int cnt = 0;
  if (flag) {
    const uint8_t* mb = (const uint8_t*)maskp;
    for (int i = t; i < T_SEQ; i += 256) cnt += (mb[(size_t)b * T_SEQ + i] == 0);
  } else {
    const int* mi = (const int*)maskp;
    for (int i = t; i < T_SEQ; i += 256) cnt += (mi[(size_t)b * T_SEQ + i] == 0);
  }
  red[t] = cnt;
  __syncthreads();
  for (int s = 128; s > 0; s >>= 1) {
    if (t < s) red[t] += red[t + s];
    __syncthreads();
  }
  if (t == 0) lengths[b] = red[0];
}

// ---------------- GEMM: C[M,N] = A[M,K] * Bt[N,K]^T + bias ----------------
// 128x128 tile, BK=64, 4 waves, mfma_f32_16x16x32_bf16, XOR-swizzled LDS.
// PADDED-ROW SKIP (r13): fully-padded M-tiles (tt0 >= len[b], only tiles
// 8..15 of each batch since len >= T/2) are dead work: MODE 0 outputs are
// never read by attention (q <= ceil128(len), keys <= lenceil <= ceil128);
// MODE 1 outputs are all-zero -> vectorized zero-fill (d_out poisoned once,
// so zeros must still be written). Uniform early-exit before any barrier.
// MODE 0: n<2048 -> Q/K [b,h,t,d] via LDS bounce; n>=2048 -> V transposed
// to Vt [b,h,d,t] via in-LDS 128x128 transpose. MODE 1: fp32 out + zeroing.
template <int MODE>
__global__ __launch_bounds__(256, 2) void gemm_bf16(
    const u16* __restrict__ A, const u16* __restrict__ Bt,
    const float* __restrict__ bias,
    u16* __restrict__ Qb, u16* __restrict__ Kb, u16* __restrict__ Vt,
    float* __restrict__ Out, const int* __restrict__ lengths,
    int Mdim, int Ndim, int Kdim) {
  __shared__ u16 SM[16384];           // As = SM[0:8192], Bs = SM[8192:16384]
  u16* As = SM;
  u16* Bs = SM + 8192;
  const int t = threadIdx.x;
  const int lane = t & 63, wid = t >> 6;
  const int wr = wid >> 1, wc = wid & 1;
  const int r16 = lane & 15, kg = lane >> 4;
  const int m0 = blockIdx.y * 128, n0 = blockIdx.x * 128;
  const int bb = m0 >> 11, tt0 = m0 & 2047;   // batch, within-batch t offset

  if (tt0 >= lengths[bb]) {                   // fully-padded M-tile (uniform)
    if (MODE == 1) {
      // outputs must be zero (and d_out starts poisoned): float4 zero-fill
      const float4 z4 = make_float4(0.f, 0.f, 0.f, 0.f);
#pragma unroll
      for (int i = 0; i < 16; i++) {
        int u = i * 256 + t;                  // 0..4095 float4 slots
        int r = u >> 5, c4 = u & 31;          // 32 float4 per 128-col row
        *(float4*)&Out[(size_t)(m0 + r) * CDIM + n0 + c4 * 4] = z4;
      }
    }
    return;                                   // MODE 0: outputs never read
  }

  f32x4 acc[4][4];
#pragma unroll
  for (int i = 0; i < 4; i++)
#pragma unroll
    for (int j = 0; j < 4; j++) acc[i][j] = (f32x4){0.f, 0.f, 0.f, 0.f};

  for (int k0 = 0; k0 < Kdim; k0 += 64) {
#pragma unroll
    for (int i = 0; i < 4; i++) {
      int idx = i * 256 + t;           // 0..1023
      int row = idx >> 3;              // 0..127
      int chunk = idx & 7;
      int colel = (chunk * 8) ^ ((row & 7) << 3);
      gld_lds16(&A[(size_t)(m0 + row) * Kdim + k0 + colel], &As[idx * 8]);
      gld_lds16(&Bt[(size_t)(n0 + row) * Kdim + k0 + colel], &Bs[idx * 8]);
    }
    __syncthreads();

#pragma unroll
    for (int s = 0; s < 2; s++) {
      bf16x8 af[4], bfr[4];
#pragma unroll
      for (int m = 0; m < 4; m++) {
        int row = wr * 64 + m * 16 + r16;
        int colel = (s * 32 + kg * 8) ^ ((row & 7) << 3);
        af[m] = *(const bf16x8*)&As[row * 64 + colel];
      }
#pragma unroll
      for (int n = 0; n < 4; n++) {
        int row = wc * 64 + n * 16 + r16;
        int colel = (s * 32 + kg * 8) ^ ((row & 7) << 3);
        bfr[n] = *(const bf16x8*)&Bs[row * 64 + colel];
      }
#pragma unroll
      for (int m = 0; m < 4; m++)
#pragma unroll
        for (int n = 0; n < 4; n++)
          acc[m][n] = __builtin_amdgcn_mfma_f32_16x16x32_bf16(
              af[m], bfr[n], acc[m][n], 0, 0, 0);
    }
    __syncthreads();
  }

  // epilogue: C/D layout col=lane&15, row=(lane>>4)*4+reg
  if (MODE == 0) {
    const int b = bb;
    if (n0 >= 2048) {
      // V block -> transpose via LDS, write Vt[b,h,d,t] coalesced
      u16* Tt = SM;  // [128][128], chunk-swizzled
#pragma unroll
      for (int m = 0; m < 4; m++)
#pragma unroll
        for (int n = 0; n < 4; n++) {
          int ln = wc * 64 + n * 16 + r16;     // local n (d-ish)
          float bv = bias[n0 + ln];
#pragma unroll
          for (int reg = 0; reg < 4; reg++) {
            int lm = wr * 64 + m * 16 + kg * 4 + reg;  // local m (t)
            Tt[ln * 128 + (lm ^ ((ln & 7) << 3))] = f2bf(acc[m][n][reg] + bv);
          }
        }
      __syncthreads();
      const int cbase = n0 - 2048;
#pragma unroll
      for (int i = 0; i < 8; i++) {
        int u = i * 256 + t;
        int ln = u >> 4, ch = u & 15;
        u16x8 v = *(const u16x8*)&Tt[ln * 128 + ((ch * 8) ^ ((ln & 7) << 3))];
        int c = cbase + ln, hh = c >> 6, d = c & 63;
        *(u16x8*)&Vt[(((size_t)b * NH + hh) * DH + d) * T_SEQ + tt0 + ch * 8] = v;
      }
    } else {
      // Q/K block -> LDS bounce (no transpose), 16B stores to [b,h,t,d]
      u16* Tt = SM;  // [128 t-rows][128 n-cols], col-swizzled per row
#pragma unroll
      for (int m = 0; m < 4; m++)
#pragma unroll
        for (int n = 0; n < 4; n++) {
          int ln = wc * 64 + n * 16 + r16;
          float bv = bias[n0 + ln];
#pragma unroll
          for (int reg = 0; reg < 4; reg++) {
            int lm = wr * 64 + m * 16 + kg * 4 + reg;
            Tt[lm * 128 + (ln ^ ((lm & 7) << 3))] = f2bf(acc[m][n][reg] + bv);
          }
        }
      __syncthreads();
      const int cb = n0 & 1023;             // block is entirely Q or K
      u16* dst = (n0 < 1024) ? Qb : Kb;
#pragma unroll
      for (int i = 0; i < 8; i++) {
        int u = i * 256 + t;
        int row = u >> 4, ch = u & 15;       // row = local t, ch = 8-col chunk
        u16x8 v = *(const u16x8*)&Tt[row * 128 + ((ch * 8) ^ ((row & 7) << 3))];
        int c = cb + ch * 8, hh = c >> 6, d = c & 63;
        *(u16x8*)&dst[((size_t)(b * NH + hh) * T_SEQ + tt0 + row) * DH + d] = v;
      }
    }
    return;
  }

#pragma unroll
  for (int m = 0; m < 4; m++) {
    int gmb = m0 + wr * 64 + m * 16 + kg * 4;
#pragma unroll
    for (int n = 0; n < 4; n++) {
      int gn = n0 + wc * 64 + n * 16 + r16;
      float bv = bias[gn];
#pragma unroll
      for (int reg = 0; reg < 4; reg++) {
        float v = acc[m][n][reg] + bv;
        int row = gmb + reg;           // = b*T + t
        int b = row >> 11, tt = row & 2047;
        if (tt >= lengths[b]) v = 0.f;
        Out[(size_t)row * CDIM + gn] = v;
      }
    }
  }
}

// ---------------- flash attention, length-aware pairs, ring-4 -----------
// ROUND-7/12-PROVEN kernel (131 us) with ONE delta: s_setprio removed
// (m190 evidence: setprio hurts barrier-lockstep structures; our 4 waves
// are lockstep). Ring-4 LDS, 1 barrier/iter, counted vmcnt(8/4/0),
// __shfl_xor softmax reduce, length-aware pairing {iq, nAct-1-iq}.
__global__ __launch_bounds__(256) void attn32p_kernel(
    const u16* __restrict__ Qb, const u16* __restrict__ Kb,
    const u16* __restrict__ Vt, u16* __restrict__ yb,
    const int* __restrict__ lengths) {
  __shared__ __attribute__((aligned(16))) char smem[65536];  // 4 x (8K K + 8K V)
  const int t = threadIdx.x, lane = t & 63, wid = t >> 6;
  const int l31 = lane & 31, hi = lane >> 5;
  const int bh = blockIdx.y, b = bh >> 4, h = bh & (NH - 1);
  const int len = lengths[b];
  const int nAct = (len + 127) >> 7;         // active q-tiles (8..16)
  const int npairs = (nAct + 1) >> 1;
  const int iq = blockIdx.x;                 // 0..7
  if (iq >= npairs) return;                  // uniform, before any barrier
  const int q0L = iq * 128;
  const int q0H = (nAct - 1 - iq) * 128;
  const bool hiAct = q0H > q0L;              // middle tile pairs with itself
  const int q0Lw = q0L + wid * 32, q0Hw = q0H + wid * 32;
  const int qrowL = q0Lw + l31, qrowH = q0Hw + l31;
  const u16* Qh = Qb + (size_t)bh * T_SEQ * DH;
  const u16* Kh = Kb + (size_t)bh * T_SEQ * DH;
  const u16* Vth = Vt + (size_t)bh * DH * T_SEQ;
  const float SC = 0.18033688011112042f;     // log2(e) / sqrt(64)
  const float THR = 44.3614195558365f;       // 8 / SC (raw-domain defer thr)

  const int lenceil = (len + 63) & ~63;
  const int kvH = (q0H + 128 < lenceil) ? q0H + 128 : lenceil;
  const int kvL = (q0L + 128 < lenceil) ? q0L + 128 : lenceil;
  const int kv_end = hiAct ? kvH : kvL;
  const int ntiles = kv_end >> 6;            // >= 2 always

  // Q B-fragments for both tiles: B[n=q=l31][k=d=ks*16+hi*8+i]
  bf16x8 qfL[4], qfH[4];
#pragma unroll
  for (int ks = 0; ks < 4; ks++) {
    qfL[ks] = *(const bf16x8*)&Qh[(size_t)qrowL * DH + ks * 16 + hi * 8];
    qfH[ks] = *(const bf16x8*)&Qh[(size_t)qrowH * DH + ks * 16 + hi * 8];
  }

  f32x16 oaccL[2], oaccH[2];
  oaccL[0] = (f32x16)0.f; oaccL[1] = (f32x16)0.f;
  oaccH[0] = (f32x16)0.f; oaccH[1] = (f32x16)0.f;
  float mL = NEGBIG, lL = 0.f, mH = NEGBIG, lH = 0.f;

  // per-lane staging sources (running ptrs; K +8192B/tile, V +128B/tile)
  const int idx0 = t, idx1 = 256 + t;
  const int row0 = idx0 >> 3, ch0 = idx0 & 7;
  const int row1 = idx1 >> 3, ch1 = idx1 & 7;
  const int kc0 = (ch0 * 8) ^ ((row0 & 7) << 3);
  const int kc1 = (ch1 * 8) ^ ((row1 & 7) << 3);
  const char* kp0 = (const char*)Kh + ((size_t)row0 * DH + kc0) * 2;
  const char* kp1 = (const char*)Kh + ((size_t)row1 * DH + kc1) * 2;
  const char* vp0 = (const char*)Vth + ((size_t)row0 * T_SEQ + kc0) * 2;
  const char* vp1 = (const char*)Vth + ((size_t)row1 * T_SEQ + kc1) * 2;

  auto STAGE = [&](int bsel) {               // 4 vm-ops per thread
    char* base = smem + bsel * 16384;
    gld_lds16(kp0, base + idx0 * 16);
    gld_lds16(kp1, base + idx1 * 16);
    gld_lds16(vp0, base + 8192 + idx0 * 16);
    gld_lds16(vp1, base + 8192 + idx1 * 16);
    kp0 += 8192; kp1 += 8192; vp0 += 128; vp1 += 128;
  };

  // one flash step for one q-tile on the staged (Ks,Vts) KV tile
  auto FLASH = [&](const u16* Ks, const u16* Vts, int kv0, int q0w, int qrow,
                   bf16x8* qf, f32x16* oacc, float& mrun, float& lrun) {
    f32x16 sacc[2];
    sacc[0] = (f32x16)0.f; sacc[1] = (f32x16)0.f;
#pragma unroll
    for (int kb = 0; kb < 2; kb++)
#pragma unroll
      for (int ks = 0; ks < 4; ks++) {
        int row = kb * 32 + l31;
        int col = (ks * 16 + hi * 8) ^ ((row & 7) << 3);
        bf16x8 ak = *(const bf16x8*)&Ks[row * 64 + col];
        sacc[kb] = __builtin_amdgcn_mfma_f32_32x32x16_bf16(
            ak, qf[ks], sacc[kb], 0, 0, 0);
      }

    if ((kv0 + 63 > q0w) || (kv0 + 64 > len)) {   // mask (raw domain)
#pragma unroll
      for (int kb = 0; kb < 2; kb++)
#pragma unroll
        for (int r = 0; r < 16; r++) {
          int key = kv0 + kb * 32 + (r & 3) + 8 * (r >> 2) + 4 * hi;
          if (key > qrow || key >= len) sacc[kb][r] = NEGBIG;
        }
    }
    // tree max (depth 5) + cross-half shfl
    float tm[16];
#pragma unroll
    for (int r = 0; r < 16; r++) tm[r] = fmaxf(sacc[0][r], sacc[1][r]);
#pragma unroll
    for (int r = 0; r < 8; r++) tm[r] = fmaxf(tm[r], tm[r + 8]);
#pragma unroll
    for (int r = 0; r < 4; r++) tm[r] = fmaxf(tm[r], tm[r + 4]);
    tm[0] = fmaxf(fmaxf(tm[0], tm[2]), fmaxf(tm[1], tm[3]));
    float mt = fmaxf(tm[0], __shfl_xor(tm[0], 32));

    if (!__all(mt <= mrun + THR)) {          // defer-max (T13)
      float mnew = fmaxf(mrun, mt);
      float fac = exp2f((mrun - mnew) * SC);
      mrun = mnew;
      lrun *= fac;
#pragma unroll
      for (int r = 0; r < 16; r++) { oacc[0][r] *= fac; oacc[1][r] *= fac; }
    }
    const float msc = mrun * SC;
#pragma unroll
    for (int kb = 0; kb < 2; kb++)
#pragma unroll
      for (int r = 0; r < 16; r++)
        sacc[kb][r] = exp2f(fmaf(sacc[kb][r], SC, -msc));
    float pt[16];
#pragma unroll
    for (int r = 0; r < 16; r++) pt[r] = sacc[0][r] + sacc[1][r];
#pragma unroll
    for (int r = 0; r < 8; r++) pt[r] += pt[r + 8];
#pragma unroll
    for (int r = 0; r < 4; r++) pt[r] += pt[r + 4];
    float ps = (pt[0] + pt[2]) + (pt[1] + pt[3]);
    ps += __shfl_xor(ps, 32);
    lrun += ps;

    // O^T += V^T * P^T (slot-permuted, zero cross-lane traffic)
#pragma unroll
    for (int ks = 0; ks < 4; ks++) {
      const int kb = ks >> 1, rb = (ks & 1) * 8;
      uint32_t d0, d1, d2, d3;
      asm("v_cvt_pk_bf16_f32 %0, %1, %2" : "=v"(d0)
          : "v"(sacc[kb][rb + 0]), "v"(sacc[kb][rb + 1]));
      asm("v_cvt_pk_bf16_f32 %0, %1, %2" : "=v"(d1)
          : "v"(sacc[kb][rb + 2]), "v"(sacc[kb][rb + 3]));
      asm("v_cvt_pk_bf16_f32 %0, %1, %2" : "=v"(d2)
          : "v"(sacc[kb][rb + 4]), "v"(sacc[kb][rb + 5]));
      asm("v_cvt_pk_bf16_f32 %0, %1, %2" : "=v"(d3)
          : "v"(sacc[kb][rb + 6]), "v"(sacc[kb][rb + 7]));
      bf16x8 pb = __builtin_bit_cast(bf16x8, (u32x4){d0, d1, d2, d3});
#pragma unroll
      for (int mb = 0; mb < 2; mb++) {
        int row = mb * 32 + l31;
        int sw = (row & 7);
        bf16x4 v1 = *(const bf16x4*)&Vts[row * 64 + ((2 * ks) ^ sw) * 8 + 4 * hi];
        bf16x4 v2 = *(const bf16x4*)&Vts[row * 64 + ((2 * ks + 1) ^ sw) * 8 + 4 * hi];
        bf16x8 av;
#pragma unroll
        for (int j = 0; j < 4; j++) { av[j] = v1[j]; av[4 + j] = v2[j]; }
        oacc[mb] = __builtin_amdgcn_mfma_f32_32x32x16_bf16(
            av, pb, oacc[mb], 0, 0, 0);
      }
    }
  };

  // ring-4 pipeline: S_k issued at iter k-2; one barrier per iter
  STAGE(0); STAGE(1);
  for (int it = 0; it < ntiles; ++it) {
    if (it + 2 < ntiles) STAGE((it + 2) & 3);
    const int r = ntiles - 1 - it;
    if (r >= 2)      asm volatile("s_waitcnt vmcnt(8)" ::: "memory");
    else if (r == 1) asm volatile("s_waitcnt vmcnt(4)" ::: "memory");
    else             asm volatile("s_waitcnt vmcnt(0)" ::: "memory");
    __builtin_amdgcn_s_barrier();
    __builtin_amdgcn_sched_barrier(0);

    const u16* Ks  = (const u16*)(smem + (it & 3) * 16384);
    const u16* Vts = (const u16*)(smem + (it & 3) * 16384 + 8192);
    const int kv0 = it << 6;
    if (hiAct && kv0 <= q0Hw + 31)
      FLASH(Ks, Vts, kv0, q0Hw, qrowH, qfH, oaccH, mH, lH);
    if (kv0 <= q0Lw + 31)
      FLASH(Ks, Vts, kv0, q0Lw, qrowL, qfL, oaccL, mL, lL);
  }
  __syncthreads();  // all compute done before smem reuse as epilogue buffer

  // epilogue: O^T regs -> per-wave LDS [32 q][72 d] -> coalesced global
  u16* yt = (u16*)smem + wid * (32 * 72);
  auto EPI = [&](f32x16* oacc, float lrun, int q0w) {
    const float inv = (lrun > 0.f) ? 1.f / lrun : 0.f;
#pragma unroll
    for (int mb = 0; mb < 2; mb++)
#pragma unroll
      for (int r = 0; r < 16; r += 2) {
        int d = mb * 32 + (r & 3) + 8 * (r >> 2) + 4 * hi;
        float a0 = oacc[mb][r] * inv, a1 = oacc[mb][r + 1] * inv;
        uint32_t pw;
        asm("v_cvt_pk_bf16_f32 %0, %1, %2" : "=v"(pw) : "v"(a0), "v"(a1));
        *(uint32_t*)&yt[l31 * 72 + d] = pw;
      }
    asm volatile("s_waitcnt lgkmcnt(0)" ::: "memory");
    __builtin_amdgcn_sched_barrier(0);
#pragma unroll
    for (int pass = 0; pass < 4; pass++) {
      int rowq = pass * 8 + (lane >> 3);
      int col8 = (lane & 7) * 8;
      u16x8 v = *(const u16x8*)&yt[rowq * 72 + col8];
      *(u16x8*)&yb[((size_t)b * T_SEQ + q0w + rowq) * CDIM + h * DH + col8] = v;
    }
    asm volatile("s_waitcnt lgkmcnt(0)" ::: "memory");
    __builtin_amdgcn_sched_barrier(0);
  };
  EPI(oaccL, lL, q0Lw);
  if (hiAct) EPI(oaccH, lH, q0Hw);
}

// ---------------- launch ----------------
extern "C" void kernel_launch(void* const* d_in, const int* in_sizes, int n_in,
                              void* d_out, int out_size, void* d_ws, size_t ws_size,
                              hipStream_t stream) {
  const float* x  = (const float*)d_in[0];
  const void*  mask = d_in[1];
  const float* Wa = (const float*)d_in[2];
  const float* ba = (const float*)d_in[3];
  const float* Wp = (const float*)d_in[4];
  const float* bp = (const float*)d_in[5];
  float* out = (float*)d_out;

  char* w = (char*)d_ws;
  u16* xb  = (u16*)w; w += (size_t)MROWS * CDIM * 2;   // 16 MB (reused as yb)
  u16* WaT = (u16*)w; w += (size_t)N3 * CDIM * 2;      // 6 MB
  u16* WpT = (u16*)w; w += (size_t)CDIM * CDIM * 2;    // 2 MB
  u16* Qb  = (u16*)w; w += (size_t)MROWS * CDIM * 2;   // 16 MB
  u16* Kb  = (u16*)w; w += (size_t)MROWS * CDIM * 2;   // 16 MB
  u16* Vt  = (u16*)w; w += (size_t)MROWS * CDIM * 2;   // 16 MB  [b,h,d,t]
  int* lengths = (int*)w;                               // 16 B
  u16* yb = xb;  // alias: xb dead after QKV GEMM

  cvt_f32_bf16<<<(MROWS * CDIM / 4 + 255) / 256, 256, 0, stream>>>(x, xb, MROWS * CDIM);
  wt_tiled<<<dim3(N3 / 64, CDIM / 64), 256, 0, stream>>>(Wa, WaT, CDIM, N3);
  wt_tiled<<<dim3(CDIM / 64, CDIM / 64), 256, 0, stream>>>(Wp, WpT, CDIM, CDIM);
  len_kernel<<<BATCH, 256, 0, stream>>>(mask, lengths);

  gemm_bf16<0><<<dim3(N3 / 128, MROWS / 128), 256, 0, stream>>>(
      xb, WaT, ba, Qb, Kb, Vt, nullptr, lengths, MROWS, N3, CDIM);

  attn32p_kernel<<<dim3(8, BATCH * NH), 256, 0, stream>>>(
      Qb, Kb, Vt, yb, lengths);

  gemm_bf16<1><<<dim3(CDIM / 128, MROWS / 128), 256, 0, stream>>>(
      yb, WpT, bp, nullptr, nullptr, nullptr, out, lengths, MROWS, CDIM, CDIM);
}